// Round 5
// baseline (241.675 us; speedup 1.0000x reference)
//
#include <hip/hip_runtime.h>

typedef __bf16 bf16;
typedef __bf16 bf16x8 __attribute__((ext_vector_type(8)));
typedef float floatx4 __attribute__((ext_vector_type(4)));

static constexpr int S = 2304;     // 48*48 tokens
static constexpr int C = 1024;
static constexpr int NHEAD = 16;
static constexpr int HDIM = 64;
static constexpr int BATCH = 2;
static constexpr float QSCALE = 0.18033688011112042f;  // log2(e)/8

// ---------------------------------------------------------------------------
// 0) fp32 -> bf16 convert (weights)
// ---------------------------------------------------------------------------
__global__ __launch_bounds__(256) void k_convert(const float* __restrict__ src,
                                                 bf16* __restrict__ dst, int n8) {
  int i = blockIdx.x * 256 + threadIdx.x;
  if (i >= n8) return;
  float4 a = *(const float4*)(src + (size_t)i * 8);
  float4 b = *(const float4*)(src + (size_t)i * 8 + 4);
  bf16x8 o;
  o[0] = (bf16)a.x; o[1] = (bf16)a.y; o[2] = (bf16)a.z; o[3] = (bf16)a.w;
  o[4] = (bf16)b.x; o[5] = (bf16)b.y; o[6] = (bf16)b.z; o[7] = (bf16)b.w;
  *(bf16x8*)(dst + (size_t)i * 8) = o;
}

// ---------------------------------------------------------------------------
// 1) transpose + cast: x[b][c][t] (fp32) -> xs[(b*S+t)][c] (bf16)
// ---------------------------------------------------------------------------
__global__ __launch_bounds__(256) void k_transpose(const float* __restrict__ x,
                                                   bf16* __restrict__ xs) {
  __shared__ bf16 T[64 * 72];   // [t][c] tile, stride 72
  int c0 = blockIdx.x * 64, t0 = blockIdx.y * 64, b = blockIdx.z;
  int tid = threadIdx.x;
  const float* xb = x + (size_t)b * C * S;
#pragma unroll
  for (int it = 0; it < 4; ++it) {
    int idx = it * 256 + tid;            // 1024 float4 chunks
    int rc = idx >> 4, t4 = idx & 15;    // c-row, t-group-of-4
    float4 v = *(const float4*)(xb + (size_t)(c0 + rc) * S + t0 + t4 * 4);
    T[(t4 * 4 + 0) * 72 + rc] = (bf16)v.x;
    T[(t4 * 4 + 1) * 72 + rc] = (bf16)v.y;
    T[(t4 * 4 + 2) * 72 + rc] = (bf16)v.z;
    T[(t4 * 4 + 3) * 72 + rc] = (bf16)v.w;
  }
  __syncthreads();
  bf16* xsb = xs + (size_t)b * S * C;
#pragma unroll
  for (int it = 0; it < 2; ++it) {
    int idx = it * 256 + tid;            // 512 chunks of 8 c
    int rt = idx >> 3, c8 = idx & 7;
    bf16x8 v;
#pragma unroll
    for (int i = 0; i < 8; ++i) v[i] = T[rt * 72 + c8 * 8 + i];
    *(bf16x8*)(xsb + (size_t)(t0 + rt) * C + c0 + c8 * 8) = v;
  }
}

// ---------------------------------------------------------------------------
// async global->LDS 16B helper
// ---------------------------------------------------------------------------
__device__ __forceinline__ void g2l16(const bf16* g, bf16* l) {
  __builtin_amdgcn_global_load_lds(
      (const __attribute__((address_space(1))) void*)g,
      (__attribute__((address_space(3))) void*)l, 16, 0, 0);
}

// ---------------------------------------------------------------------------
// 2/4) GEMM  C[m][n] = A[m][:] . Bt[n][:]  (+fp32 bias, fused epilogue)
//   EPI 0: qkv -> Q (pre-scaled by log2e/8), K, Vt
//   EPI 1: out-proj -> out[b][co][t] fp32
// ---------------------------------------------------------------------------
template <int EPI>
__global__ __launch_bounds__(256) void k_gemm_bt(const bf16* __restrict__ A,
                                                 const bf16* __restrict__ Bt,
                                                 const float* __restrict__ bias,
                                                 bf16* __restrict__ q,
                                                 bf16* __restrict__ k,
                                                 bf16* __restrict__ v,
                                                 float* __restrict__ outf) {
  constexpr int K = C;
  __shared__ bf16 As[128 * 32];
  __shared__ bf16 Bs[128 * 32];
  int tid = threadIdx.x;
  int w = tid >> 6, lane = tid & 63, ln = lane & 15, quad = lane >> 4;
  int m0 = blockIdx.y * 128, n0 = blockIdx.x * 128;
  int moff = (w >> 1) * 64, noff = (w & 1) * 64;
  floatx4 acc[4][4] = {};

  for (int k0 = 0; k0 < K; k0 += 32) {
    __syncthreads();
#pragma unroll
    for (int it = 0; it < 2; ++it) {
      int cb = (it * 4 + w) * 64;       // wave-uniform chunk base
      int g = cb + lane;                // per-lane 16B chunk id (512 total)
      int row = g >> 2, c4 = g & 3;
      g2l16(A + (size_t)(m0 + row) * K + k0 + c4 * 8, As + cb * 8);
      g2l16(Bt + (size_t)(n0 + row) * K + k0 + c4 * 8, Bs + cb * 8);
    }
    __syncthreads();
    bf16x8 af[4], bfr[4];
#pragma unroll
    for (int i = 0; i < 4; ++i) {
      af[i]  = *(const bf16x8*)(As + (moff + i * 16 + ln) * 32 + quad * 8);
      bfr[i] = *(const bf16x8*)(Bs + (noff + i * 16 + ln) * 32 + quad * 8);
    }
#pragma unroll
    for (int im = 0; im < 4; ++im)
#pragma unroll
      for (int in = 0; in < 4; ++in)
        acc[im][in] = __builtin_amdgcn_mfma_f32_16x16x32_bf16(
            af[im], bfr[in], acc[im][in], 0, 0, 0);
  }

  int bidx = (m0 >= S) ? 1 : 0;   // S=2304 = 18*128: tiles never straddle
  if (EPI == 0) {
#pragma unroll
    for (int in = 0; in < 4; ++in) {
      int j = n0 + noff + in * 16 + ln;    // column in [0,3072)
      float bv = bias[j];
      int three = j >> 10;
      int head = (j >> 6) & 15;
      int hdi = j & 63;
#pragma unroll
      for (int im = 0; im < 4; ++im) {
        int mbase = m0 + moff + im * 16 + quad * 4;
        int tb = mbase - bidx * S;
        if (three == 2) {
          union { ushort4 u; bf16 h[4]; } P;
#pragma unroll
          for (int r = 0; r < 4; ++r) P.h[r] = (bf16)(acc[im][in][r] + bv);
          *(ushort4*)(v + ((size_t)(bidx * NHEAD + head) * HDIM + hdi) * S + tb) = P.u;
        } else if (three == 0) {
          // Q: fold log2(e)/8 softmax scale here (free)
          bf16* dst = q + ((size_t)(bidx * NHEAD + head) * S + tb) * HDIM + hdi;
#pragma unroll
          for (int r = 0; r < 4; ++r)
            dst[(size_t)r * HDIM] = (bf16)((acc[im][in][r] + bv) * QSCALE);
        } else {
          bf16* dst = k + ((size_t)(bidx * NHEAD + head) * S + tb) * HDIM + hdi;
#pragma unroll
          for (int r = 0; r < 4; ++r) dst[(size_t)r * HDIM] = (bf16)(acc[im][in][r] + bv);
        }
      }
    }
  } else {
#pragma unroll
    for (int in = 0; in < 4; ++in) {
      int co = n0 + noff + in * 16 + ln;
      float bv = bias[co];
#pragma unroll
      for (int im = 0; im < 4; ++im) {
        int mbase = m0 + moff + im * 16 + quad * 4;
        int tb = mbase - bidx * S;
        float4 st;
        st.x = acc[im][in][0] + bv;
        st.y = acc[im][in][1] + bv;
        st.z = acc[im][in][2] + bv;
        st.w = acc[im][in][3] + bv;
        *(float4*)(outf + ((size_t)bidx * C + co) * S + tb) = st;
      }
    }
  }
}

// ---------------------------------------------------------------------------
// 3) causal attention: 128-q tiles, transposed compute, no-max softmax,
//    double-buffered K/V prefetch, XCD-swizzled grid, mask-specialized tail.
//   Q,K: [bh][s][64] (Q pre-scaled)  Vt: [bh][64][s]  ->  z[(b*S+t)][c] bf16
//   grid.x = 576: xcd = i&7, j = i>>3 in [0,72); bh = xcd + 8*(j/18);
//   qi = 17 - (j%18)  (LPT per XCD)
// ---------------------------------------------------------------------------
__global__ __launch_bounds__(256) void k_attn(const bf16* __restrict__ Qg,
                                              const bf16* __restrict__ Kg,
                                              const bf16* __restrict__ Vtg,
                                              bf16* __restrict__ z) {
  __shared__ bf16 Ks[2][64 * 64];   // [kt][hd], 16B chunks XOR-swizzled
  __shared__ bf16 Vs[2][64 * 64];   // [hd][kt], 16B chunks XOR-swizzled
  __shared__ bf16 Pt[128 * 72];     // [q][kt], stride 72 (144B)
  int i = blockIdx.x;
  int xcd = i & 7, j = i >> 3;
  int grp = j / 18, jq = j % 18;
  int qi = 17 - jq;                 // LPT order
  int bh = xcd + 8 * grp;
  int b = bh >> 4, h = bh & 15;
  int tid = threadIdx.x;
  int w = tid >> 6, lane = tid & 63, ln = lane & 15, quad = lane >> 4;
  int q0 = qi * 128;
  int qgL = q0 + w * 16 + ln;       // lower-half q for this lane
  int qgU = qgL + 64;               // upper-half q

  const bf16* kb = Kg + (size_t)bh * S * HDIM;
  const bf16* vb = Vtg + (size_t)bh * HDIM * S;

  // staging: 512 chunks of 16B per K/V, XOR-swizzled columns
  int s_row = tid >> 3, s_c8 = tid & 7;
  int s_cs = s_c8 ^ (s_row & 7);
  int s_row2 = s_row + 32;
  int s_cs2 = s_c8 ^ (s_row2 & 7);
  size_t kOff1 = (size_t)s_row * HDIM + s_cs * 8;
  size_t kOff2 = (size_t)s_row2 * HDIM + s_cs2 * 8;
  size_t vOff1 = (size_t)s_row * S + s_cs * 8;
  size_t vOff2 = (size_t)s_row2 * S + s_cs2 * 8;

  // Q as B-operand: lane ln <-> q, k = quad*8+j (hd); pre-scaled by log2e/8
  const bf16* qbL = Qg + ((size_t)bh * S + qgL) * HDIM + quad * 8;
  const bf16* qbU = qbL + (size_t)64 * HDIM;
  bf16x8 qfL0 = *(const bf16x8*)qbL;
  bf16x8 qfL1 = *(const bf16x8*)(qbL + 32);
  bf16x8 qfU0 = *(const bf16x8*)qbU;
  bf16x8 qfU1 = *(const bf16x8*)(qbU + 32);

  float lsumL = 0.f, lsumU = 0.f;
  floatx4 oL[4] = {}, oU[4] = {};   // Ot[hd = hf*16+quad*4+r][q = ln]

  int ktMax = 2 * qi + 1;           // tiles 0..2qi+1

  // preload tile 0 into buffer 0
  g2l16(kb + kOff1, Ks[0] + tid * 8);
  g2l16(vb + vOff1, Vs[0] + tid * 8);
  g2l16(kb + kOff2, Ks[0] + (256 + tid) * 8);
  g2l16(vb + vOff2, Vs[0] + (256 + tid) * 8);

  const bf16* kbn = kb + (size_t)64 * HDIM;
  const bf16* vbn = vb + 64;

#pragma unroll 1
  for (int kt = 0; kt <= ktMax; ++kt) {
    int cur = kt & 1;
    __syncthreads();   // staging of buf[cur] complete; buf[1-cur] fully read

    if (kt < ktMax) {  // prefetch next tile into the other buffer
      bf16* kd = Ks[1 - cur];
      bf16* vd = Vs[1 - cur];
      g2l16(kbn + kOff1, kd + tid * 8);
      g2l16(vbn + vOff1, vd + tid * 8);
      g2l16(kbn + kOff2, kd + (256 + tid) * 8);
      g2l16(vbn + vOff2, vd + (256 + tid) * 8);
      kbn += (size_t)64 * HDIM;
      vbn += 64;
    }

    bool maskL = (kt == 2 * qi);      // lower-half diagonal tile
    bool skipL = (kt == 2 * qi + 1);  // lower half fully above diagonal
    bool maskU = (kt == 2 * qi + 1);  // upper-half diagonal tile

    // St = K Qt : 16kt x 16q per MFMA, both q-halves share the K fragments
    floatx4 sL[4] = {}, sU[4] = {};
#pragma unroll
    for (int kf = 0; kf < 4; ++kf) {
      int row = kf * 16 + ln;
      int sw = row & 7;
      bf16x8 k0 = *(const bf16x8*)(Ks[cur] + row * 64 + (sw ^ quad) * 8);
      bf16x8 k1 = *(const bf16x8*)(Ks[cur] + row * 64 + ((4 ^ sw) ^ quad) * 8);
      sL[kf] = __builtin_amdgcn_mfma_f32_16x16x32_bf16(k0, qfL0, sL[kf], 0, 0, 0);
      sU[kf] = __builtin_amdgcn_mfma_f32_16x16x32_bf16(k0, qfU0, sU[kf], 0, 0, 0);
      sL[kf] = __builtin_amdgcn_mfma_f32_16x16x32_bf16(k1, qfL1, sL[kf], 0, 0, 0);
      sU[kf] = __builtin_amdgcn_mfma_f32_16x16x32_bf16(k1, qfU1, sU[kf], 0, 0, 0);
    }

    // exp2 (Q pre-scaled; no max subtraction -- scores bounded), Pt write
    if (!skipL) {
      if (!maskL) {
#pragma unroll
        for (int kf = 0; kf < 4; ++kf) {
          union { ushort4 u; bf16 hh[4]; } P;
#pragma unroll
          for (int r = 0; r < 4; ++r) {
            float pv = exp2f(sL[kf][r]);
            lsumL += pv;
            P.hh[r] = (bf16)pv;
          }
          *(ushort4*)(Pt + (w * 16 + ln) * 72 + kf * 16 + quad * 4) = P.u;
        }
      } else {
#pragma unroll
        for (int kf = 0; kf < 4; ++kf) {
          union { ushort4 u; bf16 hh[4]; } P;
#pragma unroll
          for (int r = 0; r < 4; ++r) {
            int kg = kt * 64 + kf * 16 + quad * 4 + r;
            float pv = (kg > qgL) ? 0.f : exp2f(sL[kf][r]);
            lsumL += pv;
            P.hh[r] = (bf16)pv;
          }
          *(ushort4*)(Pt + (w * 16 + ln) * 72 + kf * 16 + quad * 4) = P.u;
        }
      }
    }
    if (!maskU) {
#pragma unroll
      for (int kf = 0; kf < 4; ++kf) {
        union { ushort4 u; bf16 hh[4]; } P;
#pragma unroll
        for (int r = 0; r < 4; ++r) {
          float pv = exp2f(sU[kf][r]);
          lsumU += pv;
          P.hh[r] = (bf16)pv;
        }
        *(ushort4*)(Pt + (64 + w * 16 + ln) * 72 + kf * 16 + quad * 4) = P.u;
      }
    } else {
#pragma unroll
      for (int kf = 0; kf < 4; ++kf) {
        union { ushort4 u; bf16 hh[4]; } P;
#pragma unroll
        for (int r = 0; r < 4; ++r) {
          int kg = kt * 64 + kf * 16 + quad * 4 + r;
          float pv = (kg > qgU) ? 0.f : exp2f(sU[kf][r]);
          lsumU += pv;
          P.hh[r] = (bf16)pv;
        }
        *(ushort4*)(Pt + (64 + w * 16 + ln) * 72 + kf * 16 + quad * 4) = P.u;
      }
    }

    // Ot += V P : A = Vt rows (hd), B = Pt rows (q), k = kt
#pragma unroll
    for (int t = 0; t < 2; ++t) {
      bf16x8 pfU = *(const bf16x8*)(Pt + (64 + w * 16 + ln) * 72 + t * 32 + quad * 8);
      if (!skipL) {
        bf16x8 pfL = *(const bf16x8*)(Pt + (w * 16 + ln) * 72 + t * 32 + quad * 8);
#pragma unroll
        for (int hf = 0; hf < 4; ++hf) {
          int row = hf * 16 + ln;
          int sw = row & 7;
          bf16x8 vf = *(const bf16x8*)(Vs[cur] + row * 64 + (((t * 4 + quad) ^ sw)) * 8);
          oL[hf] = __builtin_amdgcn_mfma_f32_16x16x32_bf16(vf, pfL, oL[hf], 0, 0, 0);
          oU[hf] = __builtin_amdgcn_mfma_f32_16x16x32_bf16(vf, pfU, oU[hf], 0, 0, 0);
        }
      } else {
#pragma unroll
        for (int hf = 0; hf < 4; ++hf) {
          int row = hf * 16 + ln;
          int sw = row & 7;
          bf16x8 vf = *(const bf16x8*)(Vs[cur] + row * 64 + (((t * 4 + quad) ^ sw)) * 8);
          oU[hf] = __builtin_amdgcn_mfma_f32_16x16x32_bf16(vf, pfU, oU[hf], 0, 0, 0);
        }
      }
    }
  }

  // reduce l across the 4 quads (same q lives in lanes ln, ln+16, ln+32, ln+48)
  lsumL += __shfl_xor(lsumL, 16);
  lsumL += __shfl_xor(lsumL, 32);
  lsumU += __shfl_xor(lsumU, 16);
  lsumU += __shfl_xor(lsumU, 32);
  float invL = 1.f / lsumL;
  float invU = 1.f / lsumU;

  // z[b*S+t][h*64+hd]; 4+4 packed 8B stores
  bf16* dstL = z + ((size_t)b * S + qgL) * C + h * HDIM + quad * 4;
  bf16* dstU = z + ((size_t)b * S + qgU) * C + h * HDIM + quad * 4;
#pragma unroll
  for (int hf = 0; hf < 4; ++hf) {
    union { ushort4 u; bf16 hh[4]; } PL, PU;
#pragma unroll
    for (int r = 0; r < 4; ++r) {
      PL.hh[r] = (bf16)(oL[hf][r] * invL);
      PU.hh[r] = (bf16)(oU[hf][r] * invU);
    }
    *(ushort4*)(dstL + hf * 16) = PL.u;
    *(ushort4*)(dstU + hf * 16) = PU.u;
  }
}

// ---------------------------------------------------------------------------
extern "C" void kernel_launch(void* const* d_in, const int* in_sizes, int n_in,
                              void* d_out, int out_size, void* d_ws, size_t ws_size,
                              hipStream_t stream) {
  const float* x    = (const float*)d_in[0];
  const float* Wqkv = (const float*)d_in[1];
  const float* bqkv = (const float*)d_in[2];
  const float* Wo   = (const float*)d_in[3];
  const float* bo   = (const float*)d_in[4];
  float* out = (float*)d_out;

  bf16* ws = (bf16*)d_ws;
  const size_t tok = (size_t)BATCH * S * C;          // 4,718,592 elems
  bf16* xs   = ws;                 // [b*S][C]  (reused as z after qkv gemm)
  bf16* Qg   = ws + tok;           // [bh][S][64]
  bf16* Kg   = ws + 2 * tok;       // [bh][S][64]
  bf16* Vtg  = ws + 3 * tok;       // [bh][64][S]
  bf16* Wqb  = ws + 4 * tok;       // [3072][1024] bf16
  bf16* Wob  = Wqb + (size_t)3 * C * C;  // [1024][1024] bf16
  bf16* z    = xs;

  k_convert<<<(3 * C * C / 8 + 255) / 256, 256, 0, stream>>>(Wqkv, Wqb, 3 * C * C / 8);
  k_convert<<<(C * C / 8 + 255) / 256, 256, 0, stream>>>(Wo, Wob, C * C / 8);
  k_transpose<<<dim3(C / 64, S / 64, BATCH), 256, 0, stream>>>(x, xs);
  k_gemm_bt<0><<<dim3(3 * C / 128, BATCH * S / 128), 256, 0, stream>>>(
      xs, Wqb, bqkv, Qg, Kg, Vtg, nullptr);
  k_attn<<<dim3(576), 256, 0, stream>>>(Qg, Kg, Vtg, z);
  k_gemm_bt<1><<<dim3(C / 128, BATCH * S / 128), 256, 0, stream>>>(
      z, Wob, bo, nullptr, nullptr, nullptr, out);
}

// Round 6
// 227.681 us; speedup vs baseline: 1.0615x; 1.0615x over previous
//
#include <hip/hip_runtime.h>

typedef __bf16 bf16;
typedef __bf16 bf16x8 __attribute__((ext_vector_type(8)));
typedef float floatx4 __attribute__((ext_vector_type(4)));

static constexpr int S = 2304;     // 48*48 tokens
static constexpr int C = 1024;
static constexpr int NHEAD = 16;
static constexpr int HDIM = 64;
static constexpr int BATCH = 2;
static constexpr float QSCALE = 0.18033688011112042f;  // log2(e)/8

// ---------------------------------------------------------------------------
// 0) fp32 -> bf16 convert (weights)
// ---------------------------------------------------------------------------
__global__ __launch_bounds__(256) void k_convert(const float* __restrict__ src,
                                                 bf16* __restrict__ dst, int n8) {
  int i = blockIdx.x * 256 + threadIdx.x;
  if (i >= n8) return;
  float4 a = *(const float4*)(src + (size_t)i * 8);
  float4 b = *(const float4*)(src + (size_t)i * 8 + 4);
  bf16x8 o;
  o[0] = (bf16)a.x; o[1] = (bf16)a.y; o[2] = (bf16)a.z; o[3] = (bf16)a.w;
  o[4] = (bf16)b.x; o[5] = (bf16)b.y; o[6] = (bf16)b.z; o[7] = (bf16)b.w;
  *(bf16x8*)(dst + (size_t)i * 8) = o;
}

// ---------------------------------------------------------------------------
// 1) transpose + cast: x[b][c][t] (fp32) -> xs[(b*S+t)][c] (bf16)
// ---------------------------------------------------------------------------
__global__ __launch_bounds__(256) void k_transpose(const float* __restrict__ x,
                                                   bf16* __restrict__ xs) {
  __shared__ bf16 T[64 * 72];   // [t][c] tile, stride 72
  int c0 = blockIdx.x * 64, t0 = blockIdx.y * 64, b = blockIdx.z;
  int tid = threadIdx.x;
  const float* xb = x + (size_t)b * C * S;
#pragma unroll
  for (int it = 0; it < 4; ++it) {
    int idx = it * 256 + tid;            // 1024 float4 chunks
    int rc = idx >> 4, t4 = idx & 15;    // c-row, t-group-of-4
    float4 v = *(const float4*)(xb + (size_t)(c0 + rc) * S + t0 + t4 * 4);
    T[(t4 * 4 + 0) * 72 + rc] = (bf16)v.x;
    T[(t4 * 4 + 1) * 72 + rc] = (bf16)v.y;
    T[(t4 * 4 + 2) * 72 + rc] = (bf16)v.z;
    T[(t4 * 4 + 3) * 72 + rc] = (bf16)v.w;
  }
  __syncthreads();
  bf16* xsb = xs + (size_t)b * S * C;
#pragma unroll
  for (int it = 0; it < 2; ++it) {
    int idx = it * 256 + tid;            // 512 chunks of 8 c
    int rt = idx >> 3, c8 = idx & 7;
    bf16x8 v;
#pragma unroll
    for (int i = 0; i < 8; ++i) v[i] = T[rt * 72 + c8 * 8 + i];
    *(bf16x8*)(xsb + (size_t)(t0 + rt) * C + c0 + c8 * 8) = v;
  }
}

// ---------------------------------------------------------------------------
// async global->LDS 16B helper
// ---------------------------------------------------------------------------
__device__ __forceinline__ void g2l16(const bf16* g, bf16* l) {
  __builtin_amdgcn_global_load_lds(
      (const __attribute__((address_space(1))) void*)g,
      (__attribute__((address_space(3))) void*)l, 16, 0, 0);
}

// ---------------------------------------------------------------------------
// 2/4) GEMM  C[m][n] = A[m][:] . Bt[n][:]  (+fp32 bias, fused epilogue)
//   EPI 0: qkv -> Q (pre-scaled by log2e/8), K, Vt
//   EPI 1: out-proj -> out[b][co][t] fp32
// ---------------------------------------------------------------------------
template <int EPI>
__global__ __launch_bounds__(256) void k_gemm_bt(const bf16* __restrict__ A,
                                                 const bf16* __restrict__ Bt,
                                                 const float* __restrict__ bias,
                                                 bf16* __restrict__ q,
                                                 bf16* __restrict__ k,
                                                 bf16* __restrict__ v,
                                                 float* __restrict__ outf) {
  constexpr int K = C;
  __shared__ bf16 As[128 * 32];
  __shared__ bf16 Bs[128 * 32];
  int tid = threadIdx.x;
  int w = tid >> 6, lane = tid & 63, ln = lane & 15, quad = lane >> 4;
  int m0 = blockIdx.y * 128, n0 = blockIdx.x * 128;
  int moff = (w >> 1) * 64, noff = (w & 1) * 64;
  floatx4 acc[4][4] = {};

  for (int k0 = 0; k0 < K; k0 += 32) {
    __syncthreads();
#pragma unroll
    for (int it = 0; it < 2; ++it) {
      int cb = (it * 4 + w) * 64;       // wave-uniform chunk base
      int g = cb + lane;                // per-lane 16B chunk id (512 total)
      int row = g >> 2, c4 = g & 3;
      g2l16(A + (size_t)(m0 + row) * K + k0 + c4 * 8, As + cb * 8);
      g2l16(Bt + (size_t)(n0 + row) * K + k0 + c4 * 8, Bs + cb * 8);
    }
    __syncthreads();
    bf16x8 af[4], bfr[4];
#pragma unroll
    for (int i = 0; i < 4; ++i) {
      af[i]  = *(const bf16x8*)(As + (moff + i * 16 + ln) * 32 + quad * 8);
      bfr[i] = *(const bf16x8*)(Bs + (noff + i * 16 + ln) * 32 + quad * 8);
    }
#pragma unroll
    for (int im = 0; im < 4; ++im)
#pragma unroll
      for (int in = 0; in < 4; ++in)
        acc[im][in] = __builtin_amdgcn_mfma_f32_16x16x32_bf16(
            af[im], bfr[in], acc[im][in], 0, 0, 0);
  }

  int bidx = (m0 >= S) ? 1 : 0;   // S=2304 = 18*128: tiles never straddle
  if (EPI == 0) {
#pragma unroll
    for (int in = 0; in < 4; ++in) {
      int j = n0 + noff + in * 16 + ln;    // column in [0,3072)
      float bv = bias[j];
      int three = j >> 10;
      int head = (j >> 6) & 15;
      int hdi = j & 63;
#pragma unroll
      for (int im = 0; im < 4; ++im) {
        int mbase = m0 + moff + im * 16 + quad * 4;
        int tb = mbase - bidx * S;
        if (three == 2) {
          union { ushort4 u; bf16 h[4]; } P;
#pragma unroll
          for (int r = 0; r < 4; ++r) P.h[r] = (bf16)(acc[im][in][r] + bv);
          *(ushort4*)(v + ((size_t)(bidx * NHEAD + head) * HDIM + hdi) * S + tb) = P.u;
        } else if (three == 0) {
          // Q: fold log2(e)/8 softmax scale here (free)
          bf16* dst = q + ((size_t)(bidx * NHEAD + head) * S + tb) * HDIM + hdi;
#pragma unroll
          for (int r = 0; r < 4; ++r)
            dst[(size_t)r * HDIM] = (bf16)((acc[im][in][r] + bv) * QSCALE);
        } else {
          bf16* dst = k + ((size_t)(bidx * NHEAD + head) * S + tb) * HDIM + hdi;
#pragma unroll
          for (int r = 0; r < 4; ++r) dst[(size_t)r * HDIM] = (bf16)(acc[im][in][r] + bv);
        }
      }
    }
  } else {
#pragma unroll
    for (int in = 0; in < 4; ++in) {
      int co = n0 + noff + in * 16 + ln;
      float bv = bias[co];
#pragma unroll
      for (int im = 0; im < 4; ++im) {
        int mbase = m0 + moff + im * 16 + quad * 4;
        int tb = mbase - bidx * S;
        float4 st;
        st.x = acc[im][in][0] + bv;
        st.y = acc[im][in][1] + bv;
        st.z = acc[im][in][2] + bv;
        st.w = acc[im][in][3] + bv;
        *(float4*)(outf + ((size_t)bidx * C + co) * S + tb) = st;
      }
    }
  }
}

// ---------------------------------------------------------------------------
// 3) causal attention: 64-q tiles (round-4 skeleton), transposed compute,
//    no-max softmax (Q pre-scaled), double-buffered K/V prefetch,
//    XCD-swizzled LPT grid, mask only on the diagonal iteration,
//    Pt stride-64 XOR-swizzled => LDS 40960 B = 4 blocks/CU.
//   Q,K: [bh][s][64]  Vt: [bh][64][s]  ->  z[(b*S+t)][c] bf16
//   grid.x = 1152: xcd = i&7, j = i>>3 in [0,144); bh = xcd + 8*(j/36);
//   qi = 35 - (j%36)  (LPT per XCD)
// ---------------------------------------------------------------------------
__global__ __launch_bounds__(256) void k_attn(const bf16* __restrict__ Qg,
                                              const bf16* __restrict__ Kg,
                                              const bf16* __restrict__ Vtg,
                                              bf16* __restrict__ z) {
  __shared__ bf16 Ks[2][64 * 64];   // [kt][hd], 16B chunks XOR-swizzled
  __shared__ bf16 Vs[2][64 * 64];   // [hd][kt], 16B chunks XOR-swizzled
  __shared__ bf16 Pt[64 * 64];      // [q][kt], 16B chunks XOR-swizzled
  int i = blockIdx.x;
  int xcd = i & 7, j = i >> 3;
  int grp = j / 36, jq = j % 36;
  int qi = 35 - jq;                 // LPT order
  int bh = xcd + 8 * grp;
  int b = bh >> 4, h = bh & 15;
  int tid = threadIdx.x;
  int w = tid >> 6, lane = tid & 63, ln = lane & 15, quad = lane >> 4;
  int q0 = qi * 64;
  int qg = q0 + w * 16 + ln;        // this lane's q (lane dim)

  const bf16* kb = Kg + (size_t)bh * S * HDIM;
  const bf16* vb = Vtg + (size_t)bh * HDIM * S;

  // staging: 512 chunks of 16B per K/V, XOR-swizzled columns
  int s_row = tid >> 3, s_c8 = tid & 7;
  int s_cs = s_c8 ^ (s_row & 7);
  int s_row2 = s_row + 32;
  int s_cs2 = s_c8 ^ (s_row2 & 7);
  size_t kOff1 = (size_t)s_row * HDIM + s_cs * 8;
  size_t kOff2 = (size_t)s_row2 * HDIM + s_cs2 * 8;
  size_t vOff1 = (size_t)s_row * S + s_cs * 8;
  size_t vOff2 = (size_t)s_row2 * S + s_cs2 * 8;

  // Q as B-operand: lane ln <-> q, k = quad*8+j (hd); pre-scaled by log2e/8
  const bf16* qb = Qg + ((size_t)bh * S + qg) * HDIM + quad * 8;
  bf16x8 qf0 = *(const bf16x8*)qb;
  bf16x8 qf1 = *(const bf16x8*)(qb + 32);

  float lsum = 0.f;
  floatx4 o_acc[4] = {};            // Ot[hd = hf*16+quad*4+r][q = ln]

  // Pt addressing (stride 64, XOR swizzle at 16B granularity)
  int prow = w * 16 + ln;
  int psw = ln & 7;                 // prow & 7
  bf16* ptw = Pt + prow * 64 + (quad & 1) * 4;   // + swizzled chunk*8
  const bf16* ptr = Pt + prow * 64;

  // preload tile 0 into buffer 0
  g2l16(kb + kOff1, Ks[0] + tid * 8);
  g2l16(vb + vOff1, Vs[0] + tid * 8);
  g2l16(kb + kOff2, Ks[0] + (256 + tid) * 8);
  g2l16(vb + vOff2, Vs[0] + (256 + tid) * 8);

  const bf16* kbn = kb + (size_t)64 * HDIM;
  const bf16* vbn = vb + 64;

#pragma unroll 1
  for (int kt = 0; kt <= qi; ++kt) {
    int cur = kt & 1;
    __syncthreads();   // staging of buf[cur] complete; buf[1-cur] fully read

    if (kt < qi) {     // prefetch next tile into the other buffer
      bf16* kd = Ks[1 - cur];
      bf16* vd = Vs[1 - cur];
      g2l16(kbn + kOff1, kd + tid * 8);
      g2l16(vbn + vOff1, vd + tid * 8);
      g2l16(kbn + kOff2, kd + (256 + tid) * 8);
      g2l16(vbn + vOff2, vd + (256 + tid) * 8);
      kbn += (size_t)64 * HDIM;
      vbn += 64;
    }

    // St = K Qt : 16kt x 16q per MFMA, 4 kt-frags
    floatx4 s_acc[4] = {};
#pragma unroll
    for (int kf = 0; kf < 4; ++kf) {
      int row = kf * 16 + ln;
      int sw = row & 7;
      bf16x8 k0 = *(const bf16x8*)(Ks[cur] + row * 64 + (sw ^ quad) * 8);
      bf16x8 k1 = *(const bf16x8*)(Ks[cur] + row * 64 + ((4 ^ sw) ^ quad) * 8);
      s_acc[kf] = __builtin_amdgcn_mfma_f32_16x16x32_bf16(k0, qf0, s_acc[kf], 0, 0, 0);
      s_acc[kf] = __builtin_amdgcn_mfma_f32_16x16x32_bf16(k1, qf1, s_acc[kf], 0, 0, 0);
    }

    // exp2 (Q pre-scaled; no max subtraction -- scores bounded), Pt write.
    // Mask only on the diagonal iteration (kt == qi).
    if (kt < qi) {
#pragma unroll
      for (int kf = 0; kf < 4; ++kf) {
        union { ushort4 u; bf16 hh[4]; } P;
#pragma unroll
        for (int r = 0; r < 4; ++r) {
          float pv = exp2f(s_acc[kf][r]);
          lsum += pv;
          P.hh[r] = (bf16)pv;
        }
        *(ushort4*)(ptw + (((kf * 2 + (quad >> 1)) ^ psw)) * 8) = P.u;
      }
    } else {
#pragma unroll
      for (int kf = 0; kf < 4; ++kf) {
        union { ushort4 u; bf16 hh[4]; } P;
#pragma unroll
        for (int r = 0; r < 4; ++r) {
          int kl = kf * 16 + quad * 4 + r;          // k within tile
          float pv = (kl > w * 16 + ln) ? 0.f : exp2f(s_acc[kf][r]);
          lsum += pv;
          P.hh[r] = (bf16)pv;
        }
        *(ushort4*)(ptw + (((kf * 2 + (quad >> 1)) ^ psw)) * 8) = P.u;
      }
    }

    // Ot += V P : A = Vt rows (hd), B = Pt rows (q), k = kt
#pragma unroll
    for (int t = 0; t < 2; ++t) {
      bf16x8 pf = *(const bf16x8*)(ptr + (((t * 4 + quad) ^ psw)) * 8);
#pragma unroll
      for (int hf = 0; hf < 4; ++hf) {
        int row = hf * 16 + ln;
        int sw = row & 7;
        bf16x8 vf = *(const bf16x8*)(Vs[cur] + row * 64 + (((t * 4 + quad) ^ sw)) * 8);
        o_acc[hf] = __builtin_amdgcn_mfma_f32_16x16x32_bf16(vf, pf, o_acc[hf], 0, 0, 0);
      }
    }
  }

  // reduce l across the 4 quads (same q lives in lanes ln, ln+16, ln+32, ln+48)
  lsum += __shfl_xor(lsum, 16);
  lsum += __shfl_xor(lsum, 32);
  float inv = 1.f / lsum;

  // z[b*S+t][h*64+hd], t = qg; 4 packed 8B stores
  bf16* dst = z + ((size_t)b * S + qg) * C + h * HDIM + quad * 4;
#pragma unroll
  for (int hf = 0; hf < 4; ++hf) {
    union { ushort4 u; bf16 hh[4]; } P;
#pragma unroll
    for (int r = 0; r < 4; ++r) P.hh[r] = (bf16)(o_acc[hf][r] * inv);
    *(ushort4*)(dst + hf * 16) = P.u;
  }
}

// ---------------------------------------------------------------------------
extern "C" void kernel_launch(void* const* d_in, const int* in_sizes, int n_in,
                              void* d_out, int out_size, void* d_ws, size_t ws_size,
                              hipStream_t stream) {
  const float* x    = (const float*)d_in[0];
  const float* Wqkv = (const float*)d_in[1];
  const float* bqkv = (const float*)d_in[2];
  const float* Wo   = (const float*)d_in[3];
  const float* bo   = (const float*)d_in[4];
  float* out = (float*)d_out;

  bf16* ws = (bf16*)d_ws;
  const size_t tok = (size_t)BATCH * S * C;          // 4,718,592 elems
  bf16* xs   = ws;                 // [b*S][C]  (reused as z after qkv gemm)
  bf16* Qg   = ws + tok;           // [bh][S][64]
  bf16* Kg   = ws + 2 * tok;       // [bh][S][64]
  bf16* Vtg  = ws + 3 * tok;       // [bh][64][S]
  bf16* Wqb  = ws + 4 * tok;       // [3072][1024] bf16
  bf16* Wob  = Wqb + (size_t)3 * C * C;  // [1024][1024] bf16
  bf16* z    = xs;

  k_convert<<<(3 * C * C / 8 + 255) / 256, 256, 0, stream>>>(Wqkv, Wqb, 3 * C * C / 8);
  k_convert<<<(C * C / 8 + 255) / 256, 256, 0, stream>>>(Wo, Wob, C * C / 8);
  k_transpose<<<dim3(C / 64, S / 64, BATCH), 256, 0, stream>>>(x, xs);
  k_gemm_bt<0><<<dim3(3 * C / 128, BATCH * S / 128), 256, 0, stream>>>(
      xs, Wqb, bqkv, Qg, Kg, Vtg, nullptr);
  k_attn<<<dim3(1152), 256, 0, stream>>>(Qg, Kg, Vtg, z);
  k_gemm_bt<1><<<dim3(C / 128, BATCH * S / 128), 256, 0, stream>>>(
      z, Wob, bo, nullptr, nullptr, nullptr, out);
}

// Round 7
// 224.344 us; speedup vs baseline: 1.0773x; 1.0149x over previous
//
#include <hip/hip_runtime.h>

typedef __bf16 bf16;
typedef __bf16 bf16x8 __attribute__((ext_vector_type(8)));
typedef float floatx4 __attribute__((ext_vector_type(4)));

static constexpr int S = 2304;     // 48*48 tokens
static constexpr int C = 1024;
static constexpr int NHEAD = 16;
static constexpr int HDIM = 64;
static constexpr int BATCH = 2;
static constexpr float QSCALE = 0.18033688011112042f;  // log2(e)/8
static constexpr int QSPLIT = 18;  // q-tiles >= this are split into 2 chunks
static constexpr int NACC = S - QSPLIT * 64;           // 1152 accum q slots

// ---------------------------------------------------------------------------
// zero: clear Oacc+Lacc region (float4 granularity)
// ---------------------------------------------------------------------------
__global__ __launch_bounds__(256) void k_zero(float4* __restrict__ p, int n4) {
  int i = blockIdx.x * 256 + threadIdx.x;
  if (i < n4) p[i] = float4{0.f, 0.f, 0.f, 0.f};
}

// ---------------------------------------------------------------------------
// 0) fp32 -> bf16 convert (weights)
// ---------------------------------------------------------------------------
__global__ __launch_bounds__(256) void k_convert(const float* __restrict__ src,
                                                 bf16* __restrict__ dst, int n8) {
  int i = blockIdx.x * 256 + threadIdx.x;
  if (i >= n8) return;
  float4 a = *(const float4*)(src + (size_t)i * 8);
  float4 b = *(const float4*)(src + (size_t)i * 8 + 4);
  bf16x8 o;
  o[0] = (bf16)a.x; o[1] = (bf16)a.y; o[2] = (bf16)a.z; o[3] = (bf16)a.w;
  o[4] = (bf16)b.x; o[5] = (bf16)b.y; o[6] = (bf16)b.z; o[7] = (bf16)b.w;
  *(bf16x8*)(dst + (size_t)i * 8) = o;
}

// ---------------------------------------------------------------------------
// 1) transpose + cast: x[b][c][t] (fp32) -> xs[(b*S+t)][c] (bf16)
// ---------------------------------------------------------------------------
__global__ __launch_bounds__(256) void k_transpose(const float* __restrict__ x,
                                                   bf16* __restrict__ xs) {
  __shared__ bf16 T[64 * 72];   // [t][c] tile, stride 72
  int c0 = blockIdx.x * 64, t0 = blockIdx.y * 64, b = blockIdx.z;
  int tid = threadIdx.x;
  const float* xb = x + (size_t)b * C * S;
#pragma unroll
  for (int it = 0; it < 4; ++it) {
    int idx = it * 256 + tid;            // 1024 float4 chunks
    int rc = idx >> 4, t4 = idx & 15;    // c-row, t-group-of-4
    float4 v = *(const float4*)(xb + (size_t)(c0 + rc) * S + t0 + t4 * 4);
    T[(t4 * 4 + 0) * 72 + rc] = (bf16)v.x;
    T[(t4 * 4 + 1) * 72 + rc] = (bf16)v.y;
    T[(t4 * 4 + 2) * 72 + rc] = (bf16)v.z;
    T[(t4 * 4 + 3) * 72 + rc] = (bf16)v.w;
  }
  __syncthreads();
  bf16* xsb = xs + (size_t)b * S * C;
#pragma unroll
  for (int it = 0; it < 2; ++it) {
    int idx = it * 256 + tid;            // 512 chunks of 8 c
    int rt = idx >> 3, c8 = idx & 7;
    bf16x8 v;
#pragma unroll
    for (int i = 0; i < 8; ++i) v[i] = T[rt * 72 + c8 * 8 + i];
    *(bf16x8*)(xsb + (size_t)(t0 + rt) * C + c0 + c8 * 8) = v;
  }
}

// ---------------------------------------------------------------------------
// async global->LDS 16B helper
// ---------------------------------------------------------------------------
__device__ __forceinline__ void g2l16(const bf16* g, bf16* l) {
  __builtin_amdgcn_global_load_lds(
      (const __attribute__((address_space(1))) void*)g,
      (__attribute__((address_space(3))) void*)l, 16, 0, 0);
}

// ---------------------------------------------------------------------------
// 2/4) GEMM  C[m][n] = A[m][:] . Bt[n][:]  (+fp32 bias, fused epilogue)
//   EPI 0: qkv -> Q (pre-scaled by log2e/8), K, Vt
//   EPI 1: out-proj -> out[b][co][t] fp32
// ---------------------------------------------------------------------------
template <int EPI>
__global__ __launch_bounds__(256) void k_gemm_bt(const bf16* __restrict__ A,
                                                 const bf16* __restrict__ Bt,
                                                 const float* __restrict__ bias,
                                                 bf16* __restrict__ q,
                                                 bf16* __restrict__ k,
                                                 bf16* __restrict__ v,
                                                 float* __restrict__ outf) {
  constexpr int K = C;
  __shared__ bf16 As[128 * 32];
  __shared__ bf16 Bs[128 * 32];
  int tid = threadIdx.x;
  int w = tid >> 6, lane = tid & 63, ln = lane & 15, quad = lane >> 4;
  int m0 = blockIdx.y * 128, n0 = blockIdx.x * 128;
  int moff = (w >> 1) * 64, noff = (w & 1) * 64;
  floatx4 acc[4][4] = {};

  for (int k0 = 0; k0 < K; k0 += 32) {
    __syncthreads();
#pragma unroll
    for (int it = 0; it < 2; ++it) {
      int cb = (it * 4 + w) * 64;       // wave-uniform chunk base
      int g = cb + lane;                // per-lane 16B chunk id (512 total)
      int row = g >> 2, c4 = g & 3;
      g2l16(A + (size_t)(m0 + row) * K + k0 + c4 * 8, As + cb * 8);
      g2l16(Bt + (size_t)(n0 + row) * K + k0 + c4 * 8, Bs + cb * 8);
    }
    __syncthreads();
    bf16x8 af[4], bfr[4];
#pragma unroll
    for (int i = 0; i < 4; ++i) {
      af[i]  = *(const bf16x8*)(As + (moff + i * 16 + ln) * 32 + quad * 8);
      bfr[i] = *(const bf16x8*)(Bs + (noff + i * 16 + ln) * 32 + quad * 8);
    }
#pragma unroll
    for (int im = 0; im < 4; ++im)
#pragma unroll
      for (int in = 0; in < 4; ++in)
        acc[im][in] = __builtin_amdgcn_mfma_f32_16x16x32_bf16(
            af[im], bfr[in], acc[im][in], 0, 0, 0);
  }

  int bidx = (m0 >= S) ? 1 : 0;   // S=2304 = 18*128: tiles never straddle
  if (EPI == 0) {
#pragma unroll
    for (int in = 0; in < 4; ++in) {
      int j = n0 + noff + in * 16 + ln;    // column in [0,3072)
      float bv = bias[j];
      int three = j >> 10;
      int head = (j >> 6) & 15;
      int hdi = j & 63;
#pragma unroll
      for (int im = 0; im < 4; ++im) {
        int mbase = m0 + moff + im * 16 + quad * 4;
        int tb = mbase - bidx * S;
        if (three == 2) {
          union { ushort4 u; bf16 h[4]; } P;
#pragma unroll
          for (int r = 0; r < 4; ++r) P.h[r] = (bf16)(acc[im][in][r] + bv);
          *(ushort4*)(v + ((size_t)(bidx * NHEAD + head) * HDIM + hdi) * S + tb) = P.u;
        } else if (three == 0) {
          // Q: fold log2(e)/8 softmax scale here (free)
          bf16* dst = q + ((size_t)(bidx * NHEAD + head) * S + tb) * HDIM + hdi;
#pragma unroll
          for (int r = 0; r < 4; ++r)
            dst[(size_t)r * HDIM] = (bf16)((acc[im][in][r] + bv) * QSCALE);
        } else {
          bf16* dst = k + ((size_t)(bidx * NHEAD + head) * S + tb) * HDIM + hdi;
#pragma unroll
          for (int r = 0; r < 4; ++r) dst[(size_t)r * HDIM] = (bf16)(acc[im][in][r] + bv);
        }
      }
    }
  } else {
#pragma unroll
    for (int in = 0; in < 4; ++in) {
      int co = n0 + noff + in * 16 + ln;
      float bv = bias[co];
#pragma unroll
      for (int im = 0; im < 4; ++im) {
        int mbase = m0 + moff + im * 16 + quad * 4;
        int tb = mbase - bidx * S;
        float4 st;
        st.x = acc[im][in][0] + bv;
        st.y = acc[im][in][1] + bv;
        st.z = acc[im][in][2] + bv;
        st.w = acc[im][in][3] + bv;
        *(float4*)(outf + ((size_t)bidx * C + co) * S + tb) = st;
      }
    }
  }
}

// ---------------------------------------------------------------------------
// 3) causal attention, split-K partials with exact additive merge.
//   Q pre-scaled; no-max softmax => partial (O, l) merge is a plain sum.
//   qi <  QSPLIT : single block, writes normalized z directly.
//   qi >= QSPLIT : two blocks (k-range halves), atomicAdd into Oacc/Lacc.
// ---------------------------------------------------------------------------
__global__ __launch_bounds__(256) void k_attn_part(const bf16* __restrict__ Qg,
                                                   const bf16* __restrict__ Kg,
                                                   const bf16* __restrict__ Vtg,
                                                   bf16* __restrict__ z,
                                                   float* __restrict__ Oacc,
                                                   float* __restrict__ Lacc) {
  __shared__ bf16 Ks[2][64 * 64];   // [kt][hd], 16B chunks XOR-swizzled
  __shared__ bf16 Vs[2][64 * 64];   // [hd][kt], 16B chunks XOR-swizzled
  __shared__ bf16 Pt[64 * 64];      // [q][kt], 16B chunks XOR-swizzled
  int i = blockIdx.x;
  int xcd = i & 7, j = i >> 3;
  int grp = j / 54, r = j % 54;
  int bh = xcd + 8 * grp;
  int qi, lo, hi;
  bool single = (r >= 36);
  if (!single) {
    qi = 35 - (r >> 1);
    int c = r & 1;
    lo = c * (qi + 1) / 2;
    hi = (c + 1) * (qi + 1) / 2;
  } else {
    qi = 53 - r;                     // 17 .. 0
    lo = 0;
    hi = qi + 1;
  }
  int b = bh >> 4, h = bh & 15;
  int tid = threadIdx.x;
  int w = tid >> 6, lane = tid & 63, ln = lane & 15, quad = lane >> 4;
  int q0 = qi * 64;
  int qg = q0 + w * 16 + ln;        // this lane's q (lane dim)

  const bf16* kb = Kg + (size_t)bh * S * HDIM;
  const bf16* vb = Vtg + (size_t)bh * HDIM * S;

  // staging: 512 chunks of 16B per K/V, XOR-swizzled columns
  int s_row = tid >> 3, s_c8 = tid & 7;
  int s_cs = s_c8 ^ (s_row & 7);
  int s_row2 = s_row + 32;
  int s_cs2 = s_c8 ^ (s_row2 & 7);
  size_t kOff1 = (size_t)s_row * HDIM + s_cs * 8;
  size_t kOff2 = (size_t)s_row2 * HDIM + s_cs2 * 8;
  size_t vOff1 = (size_t)s_row * S + s_cs * 8;
  size_t vOff2 = (size_t)s_row2 * S + s_cs2 * 8;

  // Q as B-operand: lane ln <-> q, k = quad*8+j (hd); pre-scaled by log2e/8
  const bf16* qb = Qg + ((size_t)bh * S + qg) * HDIM + quad * 8;
  bf16x8 qf0 = *(const bf16x8*)qb;
  bf16x8 qf1 = *(const bf16x8*)(qb + 32);

  float lsum = 0.f;
  floatx4 o_acc[4] = {};            // Ot[hd = hf*16+quad*4+r][q = ln]

  // Pt addressing (stride 64, XOR swizzle at 16B granularity)
  int prow = w * 16 + ln;
  int psw = ln & 7;                 // prow & 7
  bf16* ptw = Pt + prow * 64 + (quad & 1) * 4;
  const bf16* ptr = Pt + prow * 64;

  // preload tile lo into buffer 0
  const bf16* kb0 = kb + (size_t)lo * 64 * HDIM;
  const bf16* vb0 = vb + (size_t)lo * 64;
  g2l16(kb0 + kOff1, Ks[0] + tid * 8);
  g2l16(vb0 + vOff1, Vs[0] + tid * 8);
  g2l16(kb0 + kOff2, Ks[0] + (256 + tid) * 8);
  g2l16(vb0 + vOff2, Vs[0] + (256 + tid) * 8);

  const bf16* kbn = kb0 + (size_t)64 * HDIM;
  const bf16* vbn = vb0 + 64;

#pragma unroll 1
  for (int kt = lo; kt < hi; ++kt) {
    int cur = (kt - lo) & 1;
    __syncthreads();   // staging of buf[cur] complete; buf[1-cur] fully read

    if (kt + 1 < hi) { // prefetch next tile into the other buffer
      bf16* kd = Ks[1 - cur];
      bf16* vd = Vs[1 - cur];
      g2l16(kbn + kOff1, kd + tid * 8);
      g2l16(vbn + vOff1, vd + tid * 8);
      g2l16(kbn + kOff2, kd + (256 + tid) * 8);
      g2l16(vbn + vOff2, vd + (256 + tid) * 8);
      kbn += (size_t)64 * HDIM;
      vbn += 64;
    }

    // St = K Qt : 16kt x 16q per MFMA, 4 kt-frags
    floatx4 s_acc[4] = {};
#pragma unroll
    for (int kf = 0; kf < 4; ++kf) {
      int row = kf * 16 + ln;
      int sw = row & 7;
      bf16x8 k0 = *(const bf16x8*)(Ks[cur] + row * 64 + (sw ^ quad) * 8);
      bf16x8 k1 = *(const bf16x8*)(Ks[cur] + row * 64 + ((4 ^ sw) ^ quad) * 8);
      s_acc[kf] = __builtin_amdgcn_mfma_f32_16x16x32_bf16(k0, qf0, s_acc[kf], 0, 0, 0);
      s_acc[kf] = __builtin_amdgcn_mfma_f32_16x16x32_bf16(k1, qf1, s_acc[kf], 0, 0, 0);
    }

    // exp2, Pt write; mask only on the diagonal iteration (kt == qi).
    if (kt < qi) {
#pragma unroll
      for (int kf = 0; kf < 4; ++kf) {
        union { ushort4 u; bf16 hh[4]; } P;
#pragma unroll
        for (int rr = 0; rr < 4; ++rr) {
          float pv = exp2f(s_acc[kf][rr]);
          lsum += pv;
          P.hh[rr] = (bf16)pv;
        }
        *(ushort4*)(ptw + (((kf * 2 + (quad >> 1)) ^ psw)) * 8) = P.u;
      }
    } else {
#pragma unroll
      for (int kf = 0; kf < 4; ++kf) {
        union { ushort4 u; bf16 hh[4]; } P;
#pragma unroll
        for (int rr = 0; rr < 4; ++rr) {
          int kl = kf * 16 + quad * 4 + rr;         // k within tile
          float pv = (kl > w * 16 + ln) ? 0.f : exp2f(s_acc[kf][rr]);
          lsum += pv;
          P.hh[rr] = (bf16)pv;
        }
        *(ushort4*)(ptw + (((kf * 2 + (quad >> 1)) ^ psw)) * 8) = P.u;
      }
    }

    // Ot += V P : A = Vt rows (hd), B = Pt rows (q), k = kt
#pragma unroll
    for (int t = 0; t < 2; ++t) {
      bf16x8 pf = *(const bf16x8*)(ptr + (((t * 4 + quad) ^ psw)) * 8);
#pragma unroll
      for (int hf = 0; hf < 4; ++hf) {
        int row = hf * 16 + ln;
        int sw = row & 7;
        bf16x8 vf = *(const bf16x8*)(Vs[cur] + row * 64 + (((t * 4 + quad) ^ sw)) * 8);
        o_acc[hf] = __builtin_amdgcn_mfma_f32_16x16x32_bf16(vf, pf, o_acc[hf], 0, 0, 0);
      }
    }
  }

  // reduce l across the 4 quads (same q lives in lanes ln, ln+16, +32, +48)
  lsum += __shfl_xor(lsum, 16);
  lsum += __shfl_xor(lsum, 32);

  if (single) {
    float inv = 1.f / lsum;
    bf16* dst = z + ((size_t)b * S + qg) * C + h * HDIM + quad * 4;
#pragma unroll
    for (int hf = 0; hf < 4; ++hf) {
      union { ushort4 u; bf16 hh[4]; } P;
#pragma unroll
      for (int rr = 0; rr < 4; ++rr) P.hh[rr] = (bf16)(o_acc[hf][rr] * inv);
      *(ushort4*)(dst + hf * 16) = P.u;
    }
  } else {
    int qa = qg - QSPLIT * 64;       // accum-space q index
    if (lane < 16) atomicAdd(&Lacc[bh * NACC + qa], lsum);
#pragma unroll
    for (int hf = 0; hf < 4; ++hf)
#pragma unroll
      for (int rr = 0; rr < 4; ++rr)
        atomicAdd(&Oacc[((size_t)bh * 64 + hf * 16 + quad * 4 + rr) * NACC + qa],
                  o_acc[hf][rr]);
  }
}

// ---------------------------------------------------------------------------
// merge/normalize for split q-tiles: z[t][c] = Oacc/Lacc (with transpose)
//   grid (18, 32): q-tile (QSPLIT+x), bh
// ---------------------------------------------------------------------------
__global__ __launch_bounds__(256) void k_norm(const float* __restrict__ Oacc,
                                              const float* __restrict__ Lacc,
                                              bf16* __restrict__ z) {
  __shared__ float T[64 * 65];      // [q][hd] stride 65
  int qt = blockIdx.x, bh = blockIdx.y;
  int b = bh >> 4, h = bh & 15;
  int qrel0 = qt * 64;              // within accum space
  int q0 = QSPLIT * 64 + qrel0;     // global token q
  int tid = threadIdx.x;
  int q4 = (tid & 15) * 4, hd0 = tid >> 4;
  float4 lv = *(const float4*)(Lacc + bh * NACC + qrel0 + q4);
  float inv0 = 1.f / lv.x, inv1 = 1.f / lv.y, inv2 = 1.f / lv.z, inv3 = 1.f / lv.w;
#pragma unroll
  for (int hf = 0; hf < 4; ++hf) {
    int hd = hf * 16 + hd0;
    float4 v = *(const float4*)(Oacc + ((size_t)bh * 64 + hd) * NACC + qrel0 + q4);
    T[(q4 + 0) * 65 + hd] = v.x * inv0;
    T[(q4 + 1) * 65 + hd] = v.y * inv1;
    T[(q4 + 2) * 65 + hd] = v.z * inv2;
    T[(q4 + 3) * 65 + hd] = v.w * inv3;
  }
  __syncthreads();
#pragma unroll
  for (int it = 0; it < 2; ++it) {
    int idx = it * 256 + tid;        // 512 groups of 8 hd
    int qq = idx >> 3, c8 = idx & 7;
    bf16x8 o;
#pragma unroll
    for (int k = 0; k < 8; ++k) o[k] = (bf16)T[qq * 65 + c8 * 8 + k];
    *(bf16x8*)(z + ((size_t)b * S + q0 + qq) * C + h * HDIM + c8 * 8) = o;
  }
}

// ---------------------------------------------------------------------------
extern "C" void kernel_launch(void* const* d_in, const int* in_sizes, int n_in,
                              void* d_out, int out_size, void* d_ws, size_t ws_size,
                              hipStream_t stream) {
  const float* x    = (const float*)d_in[0];
  const float* Wqkv = (const float*)d_in[1];
  const float* bqkv = (const float*)d_in[2];
  const float* Wo   = (const float*)d_in[3];
  const float* bo   = (const float*)d_in[4];
  float* out = (float*)d_out;

  bf16* ws = (bf16*)d_ws;
  const size_t tok = (size_t)BATCH * S * C;          // 4,718,592 elems
  bf16* xs   = ws;                 // [b*S][C]  (reused as z after qkv gemm)
  bf16* Qg   = ws + tok;           // [bh][S][64]
  bf16* Kg   = ws + 2 * tok;       // [bh][S][64]
  bf16* Vtg  = ws + 3 * tok;       // [bh][64][S]
  bf16* Wqb  = ws + 4 * tok;       // [3072][1024] bf16
  bf16* Wob  = Wqb + (size_t)3 * C * C;  // [1024][1024] bf16
  float* Oacc = (float*)(Wob + (size_t)C * C);  // [32][64][NACC] fp32
  float* Lacc = Oacc + (size_t)32 * 64 * NACC;  // [32][NACC] fp32
  bf16* z    = xs;

  // zero Oacc+Lacc: 32*64*1152 + 32*1152 = 2,396,160 floats = 599,040 float4
  k_zero<<<2340, 256, 0, stream>>>((float4*)Oacc, 599040);
  k_convert<<<(3 * C * C / 8 + 255) / 256, 256, 0, stream>>>(Wqkv, Wqb, 3 * C * C / 8);
  k_convert<<<(C * C / 8 + 255) / 256, 256, 0, stream>>>(Wo, Wob, C * C / 8);
  k_transpose<<<dim3(C / 64, S / 64, BATCH), 256, 0, stream>>>(x, xs);
  k_gemm_bt<0><<<dim3(3 * C / 128, BATCH * S / 128), 256, 0, stream>>>(
      xs, Wqb, bqkv, Qg, Kg, Vtg, nullptr);
  k_attn_part<<<dim3(1728), 256, 0, stream>>>(Qg, Kg, Vtg, z, Oacc, Lacc);
  k_norm<<<dim3(18, 32), 256, 0, stream>>>(Oacc, Lacc, z);
  k_gemm_bt<1><<<dim3(C / 128, BATCH * S / 128), 256, 0, stream>>>(
      z, Wob, bo, nullptr, nullptr, nullptr, out);
}

// Round 8
// 216.960 us; speedup vs baseline: 1.1139x; 1.0340x over previous
//
#include <hip/hip_runtime.h>

typedef __bf16 bf16;
typedef __bf16 bf16x8 __attribute__((ext_vector_type(8)));
typedef float floatx4 __attribute__((ext_vector_type(4)));

static constexpr int S = 2304;     // 48*48 tokens
static constexpr int C = 1024;
static constexpr int NHEAD = 16;
static constexpr int HDIM = 64;
static constexpr int BATCH = 2;
static constexpr float QSCALE = 0.18033688011112042f;  // log2(e)/8
static constexpr int QSPLIT = 18;  // q-tiles >= this are split into 2 chunks
static constexpr int NACC = S - QSPLIT * 64;           // 1152 accum q slots

// ---------------------------------------------------------------------------
// zero: clear Oacc+Lacc region (float4 granularity)
// ---------------------------------------------------------------------------
__global__ __launch_bounds__(256) void k_zero(float4* __restrict__ p, int n4) {
  int i = blockIdx.x * 256 + threadIdx.x;
  if (i < n4) p[i] = float4{0.f, 0.f, 0.f, 0.f};
}

// ---------------------------------------------------------------------------
// 0) fp32 -> bf16 convert (weights)
// ---------------------------------------------------------------------------
__global__ __launch_bounds__(256) void k_convert(const float* __restrict__ src,
                                                 bf16* __restrict__ dst, int n8) {
  int i = blockIdx.x * 256 + threadIdx.x;
  if (i >= n8) return;
  float4 a = *(const float4*)(src + (size_t)i * 8);
  float4 b = *(const float4*)(src + (size_t)i * 8 + 4);
  bf16x8 o;
  o[0] = (bf16)a.x; o[1] = (bf16)a.y; o[2] = (bf16)a.z; o[3] = (bf16)a.w;
  o[4] = (bf16)b.x; o[5] = (bf16)b.y; o[6] = (bf16)b.z; o[7] = (bf16)b.w;
  *(bf16x8*)(dst + (size_t)i * 8) = o;
}

// ---------------------------------------------------------------------------
// 1) transpose + cast: x[b][c][t] (fp32) -> xs[(b*S+t)][c] (bf16)
// ---------------------------------------------------------------------------
__global__ __launch_bounds__(256) void k_transpose(const float* __restrict__ x,
                                                   bf16* __restrict__ xs) {
  __shared__ bf16 T[64 * 72];   // [t][c] tile, stride 72
  int c0 = blockIdx.x * 64, t0 = blockIdx.y * 64, b = blockIdx.z;
  int tid = threadIdx.x;
  const float* xb = x + (size_t)b * C * S;
#pragma unroll
  for (int it = 0; it < 4; ++it) {
    int idx = it * 256 + tid;            // 1024 float4 chunks
    int rc = idx >> 4, t4 = idx & 15;    // c-row, t-group-of-4
    float4 v = *(const float4*)(xb + (size_t)(c0 + rc) * S + t0 + t4 * 4);
    T[(t4 * 4 + 0) * 72 + rc] = (bf16)v.x;
    T[(t4 * 4 + 1) * 72 + rc] = (bf16)v.y;
    T[(t4 * 4 + 2) * 72 + rc] = (bf16)v.z;
    T[(t4 * 4 + 3) * 72 + rc] = (bf16)v.w;
  }
  __syncthreads();
  bf16* xsb = xs + (size_t)b * S * C;
#pragma unroll
  for (int it = 0; it < 2; ++it) {
    int idx = it * 256 + tid;            // 512 chunks of 8 c
    int rt = idx >> 3, c8 = idx & 7;
    bf16x8 v;
#pragma unroll
    for (int i = 0; i < 8; ++i) v[i] = T[rt * 72 + c8 * 8 + i];
    *(bf16x8*)(xsb + (size_t)(t0 + rt) * C + c0 + c8 * 8) = v;
  }
}

// ---------------------------------------------------------------------------
// async global->LDS 16B helper
// ---------------------------------------------------------------------------
__device__ __forceinline__ void g2l16(const bf16* g, bf16* l) {
  __builtin_amdgcn_global_load_lds(
      (const __attribute__((address_space(1))) void*)g,
      (__attribute__((address_space(3))) void*)l, 16, 0, 0);
}

// ---------------------------------------------------------------------------
// 2/4) GEMM  C[m][n] = A[m][:] . Bt[n][:]  (+fp32 bias, fused epilogue)
//   128x128 tile, BK=64, XOR-swizzled 16B chunks (conflict-free b128 reads),
//   32 MFMA per barrier pair, 16 K-iterations.
//   EPI 0: qkv -> Q (pre-scaled by log2e/8), K, Vt
//   EPI 1: out-proj -> out[b][co][t] fp32
// ---------------------------------------------------------------------------
template <int EPI>
__global__ __launch_bounds__(256) void k_gemm_bt(const bf16* __restrict__ A,
                                                 const bf16* __restrict__ Bt,
                                                 const float* __restrict__ bias,
                                                 bf16* __restrict__ q,
                                                 bf16* __restrict__ k,
                                                 bf16* __restrict__ v,
                                                 float* __restrict__ outf) {
  constexpr int K = C;
  __shared__ bf16 As[128 * 64];     // [row][64], chunks XOR-swizzled
  __shared__ bf16 Bs[128 * 64];
  int tid = threadIdx.x;
  int w = tid >> 6, lane = tid & 63, ln = lane & 15, quad = lane >> 4;
  int m0 = blockIdx.y * 128, n0 = blockIdx.x * 128;
  int moff = (w >> 1) * 64, noff = (w & 1) * 64;
  floatx4 acc[4][4] = {};

  // staging map: 1024 chunks of 16B per matrix; thread covers 4 each.
  // LDS chunk L = cb + lane holds source chunk (row = L>>3, c8 = (L&7)^(row&7))
  int sr[4], sc[4];
#pragma unroll
  for (int it = 0; it < 4; ++it) {
    int L = (it * 4 + w) * 64 + lane;
    sr[it] = L >> 3;
    sc[it] = (L & 7) ^ (sr[it] & 7);
  }

  for (int k0 = 0; k0 < K; k0 += 64) {
    __syncthreads();
#pragma unroll
    for (int it = 0; it < 4; ++it) {
      int cb = (it * 4 + w) * 64;       // wave-uniform chunk base
      g2l16(A + (size_t)(m0 + sr[it]) * K + k0 + sc[it] * 8, As + cb * 8);
      g2l16(Bt + (size_t)(n0 + sr[it]) * K + k0 + sc[it] * 8, Bs + cb * 8);
    }
    __syncthreads();
#pragma unroll
    for (int t = 0; t < 2; ++t) {       // two k-halves of 32
      bf16x8 af[4], bfr[4];
#pragma unroll
      for (int i = 0; i < 4; ++i) {
        int ra = moff + i * 16 + ln;
        af[i]  = *(const bf16x8*)(As + ra * 64 + (((t * 4 + quad) ^ (ra & 7))) * 8);
        int rb = noff + i * 16 + ln;
        bfr[i] = *(const bf16x8*)(Bs + rb * 64 + (((t * 4 + quad) ^ (rb & 7))) * 8);
      }
#pragma unroll
      for (int im = 0; im < 4; ++im)
#pragma unroll
        for (int in = 0; in < 4; ++in)
          acc[im][in] = __builtin_amdgcn_mfma_f32_16x16x32_bf16(
              af[im], bfr[in], acc[im][in], 0, 0, 0);
    }
  }

  int bidx = (m0 >= S) ? 1 : 0;   // S=2304 = 18*128: tiles never straddle
  if (EPI == 0) {
#pragma unroll
    for (int in = 0; in < 4; ++in) {
      int j = n0 + noff + in * 16 + ln;    // column in [0,3072)
      float bv = bias[j];
      int three = j >> 10;
      int head = (j >> 6) & 15;
      int hdi = j & 63;
#pragma unroll
      for (int im = 0; im < 4; ++im) {
        int mbase = m0 + moff + im * 16 + quad * 4;
        int tb = mbase - bidx * S;
        if (three == 2) {
          union { ushort4 u; bf16 h[4]; } P;
#pragma unroll
          for (int r = 0; r < 4; ++r) P.h[r] = (bf16)(acc[im][in][r] + bv);
          *(ushort4*)(v + ((size_t)(bidx * NHEAD + head) * HDIM + hdi) * S + tb) = P.u;
        } else if (three == 0) {
          // Q: fold log2(e)/8 softmax scale here (free)
          bf16* dst = q + ((size_t)(bidx * NHEAD + head) * S + tb) * HDIM + hdi;
#pragma unroll
          for (int r = 0; r < 4; ++r)
            dst[(size_t)r * HDIM] = (bf16)((acc[im][in][r] + bv) * QSCALE);
        } else {
          bf16* dst = k + ((size_t)(bidx * NHEAD + head) * S + tb) * HDIM + hdi;
#pragma unroll
          for (int r = 0; r < 4; ++r) dst[(size_t)r * HDIM] = (bf16)(acc[im][in][r] + bv);
        }
      }
    }
  } else {
#pragma unroll
    for (int in = 0; in < 4; ++in) {
      int co = n0 + noff + in * 16 + ln;
      float bv = bias[co];
#pragma unroll
      for (int im = 0; im < 4; ++im) {
        int mbase = m0 + moff + im * 16 + quad * 4;
        int tb = mbase - bidx * S;
        float4 st;
        st.x = acc[im][in][0] + bv;
        st.y = acc[im][in][1] + bv;
        st.z = acc[im][in][2] + bv;
        st.w = acc[im][in][3] + bv;
        *(float4*)(outf + ((size_t)bidx * C + co) * S + tb) = st;
      }
    }
  }
}

// ---------------------------------------------------------------------------
// 3) causal attention, split-K partials with exact additive merge.
//   Q pre-scaled; no-max softmax => partial (O, l) merge is a plain sum.
//   qi <  QSPLIT : single block, writes normalized z directly.
//   qi >= QSPLIT : two blocks (k-range halves), atomicAdd into Oacc/Lacc.
// ---------------------------------------------------------------------------
__global__ __launch_bounds__(256) void k_attn_part(const bf16* __restrict__ Qg,
                                                   const bf16* __restrict__ Kg,
                                                   const bf16* __restrict__ Vtg,
                                                   bf16* __restrict__ z,
                                                   float* __restrict__ Oacc,
                                                   float* __restrict__ Lacc) {
  __shared__ bf16 Ks[2][64 * 64];   // [kt][hd], 16B chunks XOR-swizzled
  __shared__ bf16 Vs[2][64 * 64];   // [hd][kt], 16B chunks XOR-swizzled
  __shared__ bf16 Pt[64 * 64];      // [q][kt], 16B chunks XOR-swizzled
  int i = blockIdx.x;
  int xcd = i & 7, j = i >> 3;
  int grp = j / 54, r = j % 54;
  int bh = xcd + 8 * grp;
  int qi, lo, hi;
  bool single = (r >= 36);
  if (!single) {
    qi = 35 - (r >> 1);
    int c = r & 1;
    lo = c * (qi + 1) / 2;
    hi = (c + 1) * (qi + 1) / 2;
  } else {
    qi = 53 - r;                     // 17 .. 0
    lo = 0;
    hi = qi + 1;
  }
  int b = bh >> 4, h = bh & 15;
  int tid = threadIdx.x;
  int w = tid >> 6, lane = tid & 63, ln = lane & 15, quad = lane >> 4;
  int q0 = qi * 64;
  int qg = q0 + w * 16 + ln;        // this lane's q (lane dim)

  const bf16* kb = Kg + (size_t)bh * S * HDIM;
  const bf16* vb = Vtg + (size_t)bh * HDIM * S;

  // staging: 512 chunks of 16B per K/V, XOR-swizzled columns
  int s_row = tid >> 3, s_c8 = tid & 7;
  int s_cs = s_c8 ^ (s_row & 7);
  int s_row2 = s_row + 32;
  int s_cs2 = s_c8 ^ (s_row2 & 7);
  size_t kOff1 = (size_t)s_row * HDIM + s_cs * 8;
  size_t kOff2 = (size_t)s_row2 * HDIM + s_cs2 * 8;
  size_t vOff1 = (size_t)s_row * S + s_cs * 8;
  size_t vOff2 = (size_t)s_row2 * S + s_cs2 * 8;

  // Q as B-operand: lane ln <-> q, k = quad*8+j (hd); pre-scaled by log2e/8
  const bf16* qb = Qg + ((size_t)bh * S + qg) * HDIM + quad * 8;
  bf16x8 qf0 = *(const bf16x8*)qb;
  bf16x8 qf1 = *(const bf16x8*)(qb + 32);

  float lsum = 0.f;
  floatx4 o_acc[4] = {};            // Ot[hd = hf*16+quad*4+r][q = ln]

  // Pt addressing (stride 64, XOR swizzle at 16B granularity)
  int prow = w * 16 + ln;
  int psw = ln & 7;                 // prow & 7
  bf16* ptw = Pt + prow * 64 + (quad & 1) * 4;
  const bf16* ptr = Pt + prow * 64;

  // preload tile lo into buffer 0
  const bf16* kb0 = kb + (size_t)lo * 64 * HDIM;
  const bf16* vb0 = vb + (size_t)lo * 64;
  g2l16(kb0 + kOff1, Ks[0] + tid * 8);
  g2l16(vb0 + vOff1, Vs[0] + tid * 8);
  g2l16(kb0 + kOff2, Ks[0] + (256 + tid) * 8);
  g2l16(vb0 + vOff2, Vs[0] + (256 + tid) * 8);

  const bf16* kbn = kb0 + (size_t)64 * HDIM;
  const bf16* vbn = vb0 + 64;

#pragma unroll 1
  for (int kt = lo; kt < hi; ++kt) {
    int cur = (kt - lo) & 1;
    __syncthreads();   // staging of buf[cur] complete; buf[1-cur] fully read

    if (kt + 1 < hi) { // prefetch next tile into the other buffer
      bf16* kd = Ks[1 - cur];
      bf16* vd = Vs[1 - cur];
      g2l16(kbn + kOff1, kd + tid * 8);
      g2l16(vbn + vOff1, vd + tid * 8);
      g2l16(kbn + kOff2, kd + (256 + tid) * 8);
      g2l16(vbn + vOff2, vd + (256 + tid) * 8);
      kbn += (size_t)64 * HDIM;
      vbn += 64;
    }

    // St = K Qt : 16kt x 16q per MFMA, 4 kt-frags
    floatx4 s_acc[4] = {};
#pragma unroll
    for (int kf = 0; kf < 4; ++kf) {
      int row = kf * 16 + ln;
      int sw = row & 7;
      bf16x8 k0 = *(const bf16x8*)(Ks[cur] + row * 64 + (sw ^ quad) * 8);
      bf16x8 k1 = *(const bf16x8*)(Ks[cur] + row * 64 + ((4 ^ sw) ^ quad) * 8);
      s_acc[kf] = __builtin_amdgcn_mfma_f32_16x16x32_bf16(k0, qf0, s_acc[kf], 0, 0, 0);
      s_acc[kf] = __builtin_amdgcn_mfma_f32_16x16x32_bf16(k1, qf1, s_acc[kf], 0, 0, 0);
    }

    // exp2, Pt write; mask only on the diagonal iteration (kt == qi).
    if (kt < qi) {
#pragma unroll
      for (int kf = 0; kf < 4; ++kf) {
        union { ushort4 u; bf16 hh[4]; } P;
#pragma unroll
        for (int rr = 0; rr < 4; ++rr) {
          float pv = exp2f(s_acc[kf][rr]);
          lsum += pv;
          P.hh[rr] = (bf16)pv;
        }
        *(ushort4*)(ptw + (((kf * 2 + (quad >> 1)) ^ psw)) * 8) = P.u;
      }
    } else {
#pragma unroll
      for (int kf = 0; kf < 4; ++kf) {
        union { ushort4 u; bf16 hh[4]; } P;
#pragma unroll
        for (int rr = 0; rr < 4; ++rr) {
          int kl = kf * 16 + quad * 4 + rr;         // k within tile
          float pv = (kl > w * 16 + ln) ? 0.f : exp2f(s_acc[kf][rr]);
          lsum += pv;
          P.hh[rr] = (bf16)pv;
        }
        *(ushort4*)(ptw + (((kf * 2 + (quad >> 1)) ^ psw)) * 8) = P.u;
      }
    }

    // Ot += V P : A = Vt rows (hd), B = Pt rows (q), k = kt
#pragma unroll
    for (int t = 0; t < 2; ++t) {
      bf16x8 pf = *(const bf16x8*)(ptr + (((t * 4 + quad) ^ psw)) * 8);
#pragma unroll
      for (int hf = 0; hf < 4; ++hf) {
        int row = hf * 16 + ln;
        int sw = row & 7;
        bf16x8 vf = *(const bf16x8*)(Vs[cur] + row * 64 + (((t * 4 + quad) ^ sw)) * 8);
        o_acc[hf] = __builtin_amdgcn_mfma_f32_16x16x32_bf16(vf, pf, o_acc[hf], 0, 0, 0);
      }
    }
  }

  // reduce l across the 4 quads (same q lives in lanes ln, ln+16, +32, +48)
  lsum += __shfl_xor(lsum, 16);
  lsum += __shfl_xor(lsum, 32);

  if (single) {
    float inv = 1.f / lsum;
    bf16* dst = z + ((size_t)b * S + qg) * C + h * HDIM + quad * 4;
#pragma unroll
    for (int hf = 0; hf < 4; ++hf) {
      union { ushort4 u; bf16 hh[4]; } P;
#pragma unroll
      for (int rr = 0; rr < 4; ++rr) P.hh[rr] = (bf16)(o_acc[hf][rr] * inv);
      *(ushort4*)(dst + hf * 16) = P.u;
    }
  } else {
    int qa = qg - QSPLIT * 64;       // accum-space q index
    if (lane < 16) atomicAdd(&Lacc[bh * NACC + qa], lsum);
#pragma unroll
    for (int hf = 0; hf < 4; ++hf)
#pragma unroll
      for (int rr = 0; rr < 4; ++rr)
        atomicAdd(&Oacc[((size_t)bh * 64 + hf * 16 + quad * 4 + rr) * NACC + qa],
                  o_acc[hf][rr]);
  }
}

// ---------------------------------------------------------------------------
// merge/normalize for split q-tiles: z[t][c] = Oacc/Lacc (with transpose)
//   grid (18, 32): q-tile (QSPLIT+x), bh
// ---------------------------------------------------------------------------
__global__ __launch_bounds__(256) void k_norm(const float* __restrict__ Oacc,
                                              const float* __restrict__ Lacc,
                                              bf16* __restrict__ z) {
  __shared__ float T[64 * 65];      // [q][hd] stride 65
  int qt = blockIdx.x, bh = blockIdx.y;
  int b = bh >> 4, h = bh & 15;
  int qrel0 = qt * 64;              // within accum space
  int q0 = QSPLIT * 64 + qrel0;     // global token q
  int tid = threadIdx.x;
  int q4 = (tid & 15) * 4, hd0 = tid >> 4;
  float4 lv = *(const float4*)(Lacc + bh * NACC + qrel0 + q4);
  float inv0 = 1.f / lv.x, inv1 = 1.f / lv.y, inv2 = 1.f / lv.z, inv3 = 1.f / lv.w;
#pragma unroll
  for (int hf = 0; hf < 4; ++hf) {
    int hd = hf * 16 + hd0;
    float4 v = *(const float4*)(Oacc + ((size_t)bh * 64 + hd) * NACC + qrel0 + q4);
    T[(q4 + 0) * 65 + hd] = v.x * inv0;
    T[(q4 + 1) * 65 + hd] = v.y * inv1;
    T[(q4 + 2) * 65 + hd] = v.z * inv2;
    T[(q4 + 3) * 65 + hd] = v.w * inv3;
  }
  __syncthreads();
#pragma unroll
  for (int it = 0; it < 2; ++it) {
    int idx = it * 256 + tid;        // 512 groups of 8 hd
    int qq = idx >> 3, c8 = idx & 7;
    bf16x8 o;
#pragma unroll
    for (int k = 0; k < 8; ++k) o[k] = (bf16)T[qq * 65 + c8 * 8 + k];
    *(bf16x8*)(z + ((size_t)b * S + q0 + qq) * C + h * HDIM + c8 * 8) = o;
  }
}

// ---------------------------------------------------------------------------
extern "C" void kernel_launch(void* const* d_in, const int* in_sizes, int n_in,
                              void* d_out, int out_size, void* d_ws, size_t ws_size,
                              hipStream_t stream) {
  const float* x    = (const float*)d_in[0];
  const float* Wqkv = (const float*)d_in[1];
  const float* bqkv = (const float*)d_in[2];
  const float* Wo   = (const float*)d_in[3];
  const float* bo   = (const float*)d_in[4];
  float* out = (float*)d_out;

  bf16* ws = (bf16*)d_ws;
  const size_t tok = (size_t)BATCH * S * C;          // 4,718,592 elems
  bf16* xs   = ws;                 // [b*S][C]  (reused as z after qkv gemm)
  bf16* Qg   = ws + tok;           // [bh][S][64]
  bf16* Kg   = ws + 2 * tok;       // [bh][S][64]
  bf16* Vtg  = ws + 3 * tok;       // [bh][64][S]
  bf16* Wqb  = ws + 4 * tok;       // [3072][1024] bf16
  bf16* Wob  = Wqb + (size_t)3 * C * C;  // [1024][1024] bf16
  float* Oacc = (float*)(Wob + (size_t)C * C);  // [32][64][NACC] fp32
  float* Lacc = Oacc + (size_t)32 * 64 * NACC;  // [32][NACC] fp32
  bf16* z    = xs;

  // zero Oacc+Lacc: 32*64*1152 + 32*1152 = 2,396,160 floats = 599,040 float4
  k_zero<<<2340, 256, 0, stream>>>((float4*)Oacc, 599040);
  k_convert<<<(3 * C * C / 8 + 255) / 256, 256, 0, stream>>>(Wqkv, Wqb, 3 * C * C / 8);
  k_convert<<<(C * C / 8 + 255) / 256, 256, 0, stream>>>(Wo, Wob, C * C / 8);
  k_transpose<<<dim3(C / 64, S / 64, BATCH), 256, 0, stream>>>(x, xs);
  k_gemm_bt<0><<<dim3(3 * C / 128, BATCH * S / 128), 256, 0, stream>>>(
      xs, Wqb, bqkv, Qg, Kg, Vtg, nullptr);
  k_attn_part<<<dim3(1728), 256, 0, stream>>>(Qg, Kg, Vtg, z, Oacc, Lacc);
  k_norm<<<dim3(18, 32), 256, 0, stream>>>(Oacc, Lacc, z);
  k_gemm_bt<1><<<dim3(C / 128, BATCH * S / 128), 256, 0, stream>>>(
      z, Wob, bo, nullptr, nullptr, nullptr, out);
}